// Round 5
// baseline (116.141 us; speedup 1.0000x reference)
//
#include <hip/hip_runtime.h>
#include <math.h>

#define SEQ 512
#define HID 256
#define NH 8
#define DH 32
#define PI_F 3.14159265358979323846f
#define SCALE_F 0.17677669529663687f  /* 1/sqrt(32) */
#define LOG2E_F 1.4426950408889634f

// ws layout (float offsets)
#define OFF_OMEGA 0
#define OFF_AMP   131072
#define OFF_PHASE 262144
#define OFF_V     393216
#define OFF_CTX   524288

// ---------------- shared 64x64-tile full-K GEMM core ----------------
// acc[i][j] += sum_k A[r0+4*rg+i][k] * W[c0+4*cg+j][k], K=HID in 4 chunks.
// LDS: A natural [r][k] stride 68 (<=2-way banks), W transposed [k][c^swz]
// with XOR-4 swizzle so transpose-write and b128 compute-read are <=2-way.
__device__ __forceinline__ void gemm_tile(
    const float* __restrict__ A, const float* __restrict__ W,
    int r0, int c0, int tid, float (&acc)[4][4],
    float* __restrict__ xs, float* __restrict__ wts)
{
#pragma unroll
    for (int i = 0; i < 4; i++)
#pragma unroll
        for (int j = 0; j < 4; j++) acc[i][j] = 0.f;

    const int rg = tid >> 4, cg = tid & 15;

    for (int k0 = 0; k0 < HID; k0 += 64) {
#pragma unroll
        for (int it = 0; it < 4; it++) {
            int idx = tid + it * 256;
            int rr = idx >> 4, f4 = idx & 15;
            float4 av = *(const float4*)(A + (r0 + rr) * HID + k0 + 4 * f4);
            *(float4*)&xs[rr * 68 + 4 * f4] = av;
            float4 wv = *(const float4*)(W + (c0 + rr) * HID + k0 + 4 * f4);
            int cw = rr ^ ((f4 & 7) << 2);
            wts[(4 * f4 + 0) * 64 + cw] = wv.x;
            wts[(4 * f4 + 1) * 64 + cw] = wv.y;
            wts[(4 * f4 + 2) * 64 + cw] = wv.z;
            wts[(4 * f4 + 3) * 64 + cw] = wv.w;
        }
        __syncthreads();
#pragma unroll
        for (int g = 0; g < 16; g++) {
            float xfa[4][4], wfa[4][4];
#pragma unroll
            for (int i = 0; i < 4; i++) {
                float4 xv = *(const float4*)&xs[(4 * rg + i) * 68 + 4 * g];
                xfa[i][0] = xv.x; xfa[i][1] = xv.y; xfa[i][2] = xv.z; xfa[i][3] = xv.w;
            }
            const int sw = (g & 7) << 2;
#pragma unroll
            for (int m = 0; m < 4; m++) {
                float4 wv = *(const float4*)&wts[(4 * g + m) * 64 + ((4 * cg) ^ sw)];
                wfa[m][0] = wv.x; wfa[m][1] = wv.y; wfa[m][2] = wv.z; wfa[m][3] = wv.w;
            }
#pragma unroll
            for (int m = 0; m < 4; m++)
#pragma unroll
                for (int i = 0; i < 4; i++)
#pragma unroll
                    for (int j = 0; j < 4; j++)
                        acc[i][j] = fmaf(xfa[i][m], wfa[m][j], acc[i][j]);
        }
        __syncthreads();
    }
}

// ---------------- QKV projection, full-K, fused activations ----------------
// grid (32, 3): x = rt(8) x ct(4), y = which {q,k,v}.
__global__ __launch_bounds__(256) void gemm_qkv_act(
    const float* __restrict__ x,
    const float* __restrict__ wq, const float* __restrict__ bq,
    const float* __restrict__ wk, const float* __restrict__ bk,
    const float* __restrict__ wv, const float* __restrict__ bv,
    float* __restrict__ ws)
{
    const int which = blockIdx.y;
    const float* W = (which == 0) ? wq : (which == 1) ? wk : wv;
    const float* B = (which == 0) ? bq : (which == 1) ? bk : bv;
    const int ct = blockIdx.x & 3;
    const int rt = blockIdx.x >> 2;
    const int r0 = rt * 64, c0 = ct * 64;

    __shared__ float xs[64 * 68];
    __shared__ float wts[64 * 64];

    const int tid = threadIdx.x;
    float acc[4][4];
    gemm_tile(x, W, r0, c0, tid, acc, xs, wts);

    const int rg = tid >> 4, cg = tid & 15;
    float4 b4 = *(const float4*)(B + c0 + 4 * cg);
    float bb[4] = {b4.x, b4.y, b4.z, b4.w};

#pragma unroll
    for (int i = 0; i < 4; i++) {
        int row = r0 + 4 * rg + i;
#pragma unroll
        for (int j = 0; j < 4; j++) {
            float val = acc[i][j] + bb[j];
            int o = row * HID + c0 + 4 * cg + j;
            if (which == 0) {
                ws[OFF_OMEGA + o] = PI_F / (1.f + expf(-val));
            } else if (which == 1) {
                ws[OFF_AMP + o] = 1.f / (1.f + expf(-val));
            } else {
                ws[OFF_V + o] = val;
                ws[OFF_PHASE + o] = PI_F * tanhf(val);
            }
        }
    }
}

// ---------------- output projection, full-K, fused bias ----------------
__global__ __launch_bounds__(256) void gemm_out(
    const float* __restrict__ ctx, const float* __restrict__ wo,
    const float* __restrict__ bo, float* __restrict__ out)
{
    const int ct = blockIdx.x & 3;
    const int rt = blockIdx.x >> 2;
    const int r0 = rt * 64, c0 = ct * 64;

    __shared__ float xs[64 * 68];
    __shared__ float wts[64 * 64];

    const int tid = threadIdx.x;
    float acc[4][4];
    gemm_tile(ctx, wo, r0, c0, tid, acc, xs, wts);

    const int rg = tid >> 4, cg = tid & 15;
    float4 b4 = *(const float4*)(bo + c0 + 4 * cg);
#pragma unroll
    for (int i = 0; i < 4; i++) {
        int row = r0 + 4 * rg + i;
        float4 o;
        o.x = acc[i][0] + b4.x;
        o.y = acc[i][1] + b4.y;
        o.z = acc[i][2] + b4.z;
        o.w = acc[i][3] + b4.w;
        *(float4*)&out[row * HID + c0 + 4 * cg] = o;
    }
}

// ---------------- wave-interference attention ----------------
// thread = (il = tid>>5, d = tid&31); grid (SEQ/8, NH). v in natural [j][col]
// layout -> one 128B txn per wave per j. Rotation recurrence (4 indep chains,
// step -4w) with amp*SCALE*log2e folded in; hw exp2 per j.
__global__ __launch_bounds__(256) void wave_attn(const float* __restrict__ ws,
                                                 float* __restrict__ ctx)
{
    const int h  = blockIdx.y;
    const int il = threadIdx.x >> 5;
    const int d  = threadIdx.x & 31;
    const int i  = blockIdx.x * 8 + il;
    const int col = h * DH + d;

    const float w  = ws[OFF_OMEGA + i * HID + col];
    const float aL = ws[OFF_AMP + i * HID + col] * (SCALE_F * LOG2E_F);
    const float ph = ws[OFF_PHASE + i * HID + col];
    const float* vcol = ws + OFF_V + col;

    float sw_, cw;
    sincosf(w, &sw_, &cw);
    float c2 = cw * cw - sw_ * sw_, s2 = 2.f * sw_ * cw;
    float c4 = c2 * c2 - s2 * s2,   s4 = 2.f * s2 * c2;

    float th0 = fmaf(w, (float)i, ph);      // angle at j=0
    float s0, cc0;
    sincosf(th0, &s0, &cc0);

    float pc[4], psn[4];
    pc[0] = cc0; psn[0] = s0;
#pragma unroll
    for (int k = 1; k < 4; k++) {           // rotate by -w per step
        float nc = pc[k - 1] * cw + psn[k - 1] * sw_;
        float ns = psn[k - 1] * cw - pc[k - 1] * sw_;
        pc[k] = nc; psn[k] = ns;
    }
    float p[4], q[4], den[4], num[4];
#pragma unroll
    for (int k = 0; k < 4; k++) {
        p[k] = aL * pc[k]; q[k] = aL * psn[k];
        den[k] = 0.f; num[k] = 0.f;
    }

#pragma unroll 4
    for (int t = 0; t < SEQ / 4; t++) {
        float v0 = vcol[(4 * t + 0) * HID];
        float v1 = vcol[(4 * t + 1) * HID];
        float v2v = vcol[(4 * t + 2) * HID];
        float v3 = vcol[(4 * t + 3) * HID];
        float e0 = __builtin_amdgcn_exp2f(p[0]);
        float e1 = __builtin_amdgcn_exp2f(p[1]);
        float e2 = __builtin_amdgcn_exp2f(p[2]);
        float e3 = __builtin_amdgcn_exp2f(p[3]);
        den[0] += e0; den[1] += e1; den[2] += e2; den[3] += e3;
        num[0] = fmaf(e0, v0, num[0]);
        num[1] = fmaf(e1, v1, num[1]);
        num[2] = fmaf(e2, v2v, num[2]);
        num[3] = fmaf(e3, v3, num[3]);
#pragma unroll
        for (int k = 0; k < 4; k++) {
            float np = p[k] * c4 + q[k] * s4;   // angle -= 4w
            float nq = q[k] * c4 - p[k] * s4;
            p[k] = np; q[k] = nq;
        }
    }
    float denom = (den[0] + den[1]) + (den[2] + den[3]);
    float numer = (num[0] + num[1]) + (num[2] + num[3]);
    ctx[i * HID + col] = numer / denom;
}

extern "C" void kernel_launch(void* const* d_in, const int* in_sizes, int n_in,
                              void* d_out, int out_size, void* d_ws, size_t ws_size,
                              hipStream_t stream) {
    const float* x  = (const float*)d_in[0];
    const float* wq = (const float*)d_in[1];
    const float* bq = (const float*)d_in[2];
    const float* wk = (const float*)d_in[3];
    const float* bk = (const float*)d_in[4];
    const float* wv = (const float*)d_in[5];
    const float* bv = (const float*)d_in[6];
    const float* wo = (const float*)d_in[7];
    const float* bo = (const float*)d_in[8];

    float* ws = (float*)d_ws;

    hipLaunchKernelGGL(gemm_qkv_act, dim3(32, 3), dim3(256), 0, stream,
                       x, wq, bq, wk, bk, wv, bv, ws);
    hipLaunchKernelGGL(wave_attn, dim3(SEQ / 8, NH), dim3(256), 0, stream,
                       ws, ws + OFF_CTX);
    hipLaunchKernelGGL(gemm_out, dim3(32), dim3(256), 0, stream,
                       ws + OFF_CTX, wo, bo, (float*)d_out);
}